// Round 1
// baseline (834.738 us; speedup 1.0000x reference)
//
#include <hip/hip_runtime.h>
#include <cstdint>
#include <cstddef>

// Problem constants (B=1, T=2048, D=1024, E=8, F=2048, K=2), fp32 everywhere.
#define N_TOK 2048
#define DIM   1024
#define NEXP  8
#define FDIM  2048
#define TOPK  2

// ---- workspace layout (bytes) ----
// counts:   NEXP ints
// toklist:  NEXP * N_TOK ints   (token ids grouped per expert)
// tokexp:   N_TOK*2 ints        (per token: its 2 experts)
// tokpos:   N_TOK*2 ints        (per token: position within expert list)
// tokgate:  N_TOK*2 floats      (per token: renormalized gate)
// Abuf:     (2*N_TOK) x FDIM floats   = 32 MiB  (fc1 activations, rows packed by expert)
// Ybuf:     (2*N_TOK) x DIM  floats   = 16 MiB  (fc2 outputs)
#define OFF_COUNTS  0
#define OFF_TOK     4096
#define OFF_TOKEXP  (OFF_TOK + NEXP * N_TOK * 4)
#define OFF_TOKPOS  (OFF_TOKEXP + N_TOK * 2 * 4)
#define OFF_TOKGATE (OFF_TOKPOS + N_TOK * 2 * 4)
#define OFF_A       (1 << 20)
#define OFF_Y       (OFF_A + (size_t)(2 * N_TOK) * FDIM * 4)
// total ws need: OFF_Y + 2*N_TOK*DIM*4  ~= 50.4 MiB

// ---------------- router: 1 wave per token ----------------
__global__ __launch_bounds__(64) void router_kernel(
    const float* __restrict__ x, const float* __restrict__ Wr,
    int* __restrict__ counts, int* __restrict__ toklist,
    int* __restrict__ tokexp, int* __restrict__ tokpos,
    float* __restrict__ tokgate) {
  int n = blockIdx.x;
  int lane = threadIdx.x;
  const float* xr = x + (size_t)n * DIM;

  // cache this token's row in registers: 16 floats per lane
  float xv[DIM / 64];
#pragma unroll
  for (int i = 0; i < DIM / 64; ++i) xv[i] = xr[lane + 64 * i];

  float logit[NEXP];
#pragma unroll
  for (int e = 0; e < NEXP; ++e) {
    const float* wr = Wr + (size_t)e * DIM;
    float s = 0.f;
#pragma unroll
    for (int i = 0; i < DIM / 64; ++i) s += xv[i] * wr[lane + 64 * i];
#pragma unroll
    for (int off = 32; off; off >>= 1) s += __shfl_down(s, off);
    logit[e] = s;  // valid on lane 0
  }

  if (lane == 0) {
    float m = logit[0];
#pragma unroll
    for (int e = 1; e < NEXP; ++e) m = fmaxf(m, logit[e]);
    float p[NEXP];
#pragma unroll
    for (int e = 0; e < NEXP; ++e) p[e] = expf(logit[e] - m);
    // top-2 (ties -> lowest index, matching jax.lax.top_k)
    int i1 = 0;
#pragma unroll
    for (int e = 1; e < NEXP; ++e) if (p[e] > p[i1]) i1 = e;
    int i2 = (i1 == 0) ? 1 : 0;
#pragma unroll
    for (int e = 0; e < NEXP; ++e)
      if (e != i1 && p[e] > p[i2]) i2 = e;
    float denom = p[i1] + p[i2];
    float g1 = p[i1] / denom;
    float g2 = p[i2] / denom;

    int pos1 = atomicAdd(&counts[i1], 1);
    toklist[i1 * N_TOK + pos1] = n;
    tokexp[n * 2 + 0] = i1; tokpos[n * 2 + 0] = pos1; tokgate[n * 2 + 0] = g1;

    int pos2 = atomicAdd(&counts[i2], 1);
    toklist[i2 * N_TOK + pos2] = n;
    tokexp[n * 2 + 1] = i2; tokpos[n * 2 + 1] = pos2; tokgate[n * 2 + 1] = g2;
  }
}

// ---------------- tiled fp32 GEMM: fc1 + relu^2 ----------------
// C[r, f] = act( sum_d x[tok[r], d] * W1[e, f, d] ), tile 64x64, BK=16, 256 thr, 4x4/thr
#define BM 64
#define BN 64
#define BK 16
#define ROWB (N_TOK / BM)  // 32 worst-case row-blocks per expert

__global__ __launch_bounds__(256) void fc1_kernel(
    const float* __restrict__ x, const float* __restrict__ W1,
    const int* __restrict__ counts, const int* __restrict__ toklist,
    float* __restrict__ Abuf) {
  const int COLB = FDIM / BN;  // 32
  int bid = blockIdx.x;
  int e  = bid / (ROWB * COLB);
  int rb = (bid / COLB) % ROWB;
  int cb = bid % COLB;
  int ne = counts[e];
  if (rb * BM >= ne) return;
  int base = 0;
  for (int i = 0; i < e; ++i) base += counts[i];

  __shared__ float As[BK][BM];
  __shared__ float Bs[BK][BN];

  int tid = threadIdx.x;
  int tx = tid % 16, ty = tid / 16;
  int srow = tid / 4;          // 0..63 staging row
  int sk4  = (tid % 4) * 4;    // 0,4,8,12

  int grow = rb * BM + srow;
  int tok = toklist[e * N_TOK + ((grow < ne) ? grow : 0)];
  const float* arow = x + (size_t)tok * DIM;
  const float* brow = W1 + ((size_t)e * FDIM + (size_t)(cb * BN + srow)) * DIM;

  float acc[4][4] = {};

  for (int k0 = 0; k0 < DIM; k0 += BK) {
    float4 av = *(const float4*)(arow + k0 + sk4);
    float4 bv = *(const float4*)(brow + k0 + sk4);
    __syncthreads();
    As[sk4 + 0][srow] = av.x; As[sk4 + 1][srow] = av.y;
    As[sk4 + 2][srow] = av.z; As[sk4 + 3][srow] = av.w;
    Bs[sk4 + 0][srow] = bv.x; Bs[sk4 + 1][srow] = bv.y;
    Bs[sk4 + 2][srow] = bv.z; Bs[sk4 + 3][srow] = bv.w;
    __syncthreads();
#pragma unroll
    for (int k = 0; k < BK; ++k) {
      float4 a4 = *(const float4*)&As[k][ty * 4];
      float4 b4 = *(const float4*)&Bs[k][tx * 4];
      acc[0][0] += a4.x * b4.x; acc[0][1] += a4.x * b4.y; acc[0][2] += a4.x * b4.z; acc[0][3] += a4.x * b4.w;
      acc[1][0] += a4.y * b4.x; acc[1][1] += a4.y * b4.y; acc[1][2] += a4.y * b4.z; acc[1][3] += a4.y * b4.w;
      acc[2][0] += a4.z * b4.x; acc[2][1] += a4.z * b4.y; acc[2][2] += a4.z * b4.z; acc[2][3] += a4.z * b4.w;
      acc[3][0] += a4.w * b4.x; acc[3][1] += a4.w * b4.y; acc[3][2] += a4.w * b4.z; acc[3][3] += a4.w * b4.w;
    }
  }

  int ocol = cb * BN + tx * 4;
#pragma unroll
  for (int i = 0; i < 4; ++i) {
    int r = rb * BM + ty * 4 + i;
    if (r < ne) {
      float4 v;
      float t;
      t = fmaxf(acc[i][0], 0.f); v.x = t * t;
      t = fmaxf(acc[i][1], 0.f); v.y = t * t;
      t = fmaxf(acc[i][2], 0.f); v.z = t * t;
      t = fmaxf(acc[i][3], 0.f); v.w = t * t;
      *(float4*)&Abuf[(size_t)(base + r) * FDIM + ocol] = v;
    }
  }
}

// ---------------- tiled fp32 GEMM: fc2 ----------------
// Y[r, d] = sum_f A[r, f] * W2[e, d, f]
__global__ __launch_bounds__(256) void fc2_kernel(
    const float* __restrict__ Abuf, const float* __restrict__ W2,
    const int* __restrict__ counts, float* __restrict__ Ybuf) {
  const int COLB = DIM / BN;  // 16
  int bid = blockIdx.x;
  int e  = bid / (ROWB * COLB);
  int rb = (bid / COLB) % ROWB;
  int cb = bid % COLB;
  int ne = counts[e];
  if (rb * BM >= ne) return;
  int base = 0;
  for (int i = 0; i < e; ++i) base += counts[i];

  __shared__ float As[BK][BM];
  __shared__ float Bs[BK][BN];

  int tid = threadIdx.x;
  int tx = tid % 16, ty = tid / 16;
  int srow = tid / 4;
  int sk4  = (tid % 4) * 4;

  int grow = rb * BM + srow;
  int arow_idx = base + ((grow < ne) ? grow : (ne - 1));
  const float* arow = Abuf + (size_t)arow_idx * FDIM;
  const float* brow = W2 + ((size_t)e * DIM + (size_t)(cb * BN + srow)) * FDIM;

  float acc[4][4] = {};

  for (int k0 = 0; k0 < FDIM; k0 += BK) {
    float4 av = *(const float4*)(arow + k0 + sk4);
    float4 bv = *(const float4*)(brow + k0 + sk4);
    __syncthreads();
    As[sk4 + 0][srow] = av.x; As[sk4 + 1][srow] = av.y;
    As[sk4 + 2][srow] = av.z; As[sk4 + 3][srow] = av.w;
    Bs[sk4 + 0][srow] = bv.x; Bs[sk4 + 1][srow] = bv.y;
    Bs[sk4 + 2][srow] = bv.z; Bs[sk4 + 3][srow] = bv.w;
    __syncthreads();
#pragma unroll
    for (int k = 0; k < BK; ++k) {
      float4 a4 = *(const float4*)&As[k][ty * 4];
      float4 b4 = *(const float4*)&Bs[k][tx * 4];
      acc[0][0] += a4.x * b4.x; acc[0][1] += a4.x * b4.y; acc[0][2] += a4.x * b4.z; acc[0][3] += a4.x * b4.w;
      acc[1][0] += a4.y * b4.x; acc[1][1] += a4.y * b4.y; acc[1][2] += a4.y * b4.z; acc[1][3] += a4.y * b4.w;
      acc[2][0] += a4.z * b4.x; acc[2][1] += a4.z * b4.y; acc[2][2] += a4.z * b4.z; acc[2][3] += a4.z * b4.w;
      acc[3][0] += a4.w * b4.x; acc[3][1] += a4.w * b4.y; acc[3][2] += a4.w * b4.z; acc[3][3] += a4.w * b4.w;
    }
  }

  int ocol = cb * BN + tx * 4;
#pragma unroll
  for (int i = 0; i < 4; ++i) {
    int r = rb * BM + ty * 4 + i;
    if (r < ne) {
      float4 v = make_float4(acc[i][0], acc[i][1], acc[i][2], acc[i][3]);
      *(float4*)&Ybuf[(size_t)(base + r) * DIM + ocol] = v;
    }
  }
}

// ---------------- combine: out[n] = g0*Y[row0] + g1*Y[row1] ----------------
__global__ __launch_bounds__(256) void combine_kernel(
    const float* __restrict__ Ybuf, const int* __restrict__ counts,
    const int* __restrict__ tokexp, const int* __restrict__ tokpos,
    const float* __restrict__ tokgate, float* __restrict__ out) {
  int n = blockIdx.x;
  int c4 = threadIdx.x * 4;

  int e0 = tokexp[n * 2 + 0], p0 = tokpos[n * 2 + 0];
  int e1 = tokexp[n * 2 + 1], p1 = tokpos[n * 2 + 1];
  float g0 = tokgate[n * 2 + 0], g1 = tokgate[n * 2 + 1];

  int b0 = 0, b1 = 0;
#pragma unroll
  for (int i = 0; i < NEXP; ++i) {
    int c = counts[i];
    if (i < e0) b0 += c;
    if (i < e1) b1 += c;
  }

  float4 y0 = *(const float4*)&Ybuf[(size_t)(b0 + p0) * DIM + c4];
  float4 y1 = *(const float4*)&Ybuf[(size_t)(b1 + p1) * DIM + c4];
  float4 o;
  o.x = g0 * y0.x + g1 * y1.x;
  o.y = g0 * y0.y + g1 * y1.y;
  o.z = g0 * y0.z + g1 * y1.z;
  o.w = g0 * y0.w + g1 * y1.w;
  *(float4*)&out[(size_t)n * DIM + c4] = o;
}

extern "C" void kernel_launch(void* const* d_in, const int* in_sizes, int n_in,
                              void* d_out, int out_size, void* d_ws, size_t ws_size,
                              hipStream_t stream) {
  const float* x  = (const float*)d_in[0];
  const float* Wr = (const float*)d_in[1];
  const float* W1 = (const float*)d_in[2];
  const float* W2 = (const float*)d_in[3];
  float* out = (float*)d_out;

  char* ws = (char*)d_ws;
  int*   counts  = (int*)(ws + OFF_COUNTS);
  int*   toklist = (int*)(ws + OFF_TOK);
  int*   tokexp  = (int*)(ws + OFF_TOKEXP);
  int*   tokpos  = (int*)(ws + OFF_TOKPOS);
  float* tokgate = (float*)(ws + OFF_TOKGATE);
  float* Abuf    = (float*)(ws + OFF_A);
  float* Ybuf    = (float*)(ws + OFF_Y);

  hipMemsetAsync(counts, 0, NEXP * sizeof(int), stream);

  router_kernel<<<N_TOK, 64, 0, stream>>>(x, Wr, counts, toklist, tokexp, tokpos, tokgate);

  fc1_kernel<<<NEXP * ROWB * (FDIM / BN), 256, 0, stream>>>(x, W1, counts, toklist, Abuf);

  fc2_kernel<<<NEXP * ROWB * (DIM / BN), 256, 0, stream>>>(Abuf, W2, counts, Ybuf);

  combine_kernel<<<N_TOK, 256, 0, stream>>>(Ybuf, counts, tokexp, tokpos, tokgate, out);
}

// Round 3
// 403.266 us; speedup vs baseline: 2.0699x; 2.0699x over previous
//
#include <hip/hip_runtime.h>
#include <hip/hip_bf16.h>
#include <cstdint>
#include <cstddef>

// B=1, T=2048, D=1024, E=8, F=2048, K=2. fp32 in/out; bf16 MFMA internally.
#define N_TOK 2048
#define DIM   1024
#define NEXP  8
#define FDIM  2048

typedef __attribute__((ext_vector_type(8))) short short8;   // 8 x bf16 (4 VGPR)
typedef __attribute__((ext_vector_type(4))) float f32x4;    // MFMA C/D
typedef unsigned short ushort_t;

// ---- workspace layout (bytes) ----
#define OFF_COUNTS  0
#define OFF_TOK     4096
#define OFF_TOKEXP  (OFF_TOK + NEXP * N_TOK * 4)
#define OFF_TOKPOS  (OFF_TOKEXP + N_TOK * 2 * 4)
#define OFF_TOKGATE (OFF_TOKPOS + N_TOK * 2 * 4)
#define OFF_A       ((size_t)1 << 20)                         // Abuf bf16: 4096 x 2048 x 2 = 16 MiB
#define OFF_Y       (OFF_A + (size_t)(2 * N_TOK) * FDIM * 2)  // Ybuf fp32: 4096 x 1024 x 4 = 16 MiB
// total ~33 MiB

// fp32 pair -> packed bf16 pair (RNE); compiler emits v_cvt_pk_bf16_f32
__device__ inline uint32_t cvt2(float lo, float hi) {
  __hip_bfloat162 p = __float22bfloat162_rn(make_float2(lo, hi));
  uint32_t r;
  __builtin_memcpy(&r, &p, 4);
  return r;
}

// ---------------- router: 1 wave per token (fp32, exact) ----------------
__global__ __launch_bounds__(64) void router_kernel(
    const float* __restrict__ x, const float* __restrict__ Wr,
    int* __restrict__ counts, int* __restrict__ toklist,
    int* __restrict__ tokexp, int* __restrict__ tokpos,
    float* __restrict__ tokgate) {
  int n = blockIdx.x;
  int lane = threadIdx.x;
  const float* xr = x + (size_t)n * DIM;

  float xv[DIM / 64];
#pragma unroll
  for (int i = 0; i < DIM / 64; ++i) xv[i] = xr[lane + 64 * i];

  float logit[NEXP];
#pragma unroll
  for (int e = 0; e < NEXP; ++e) {
    const float* wr = Wr + (size_t)e * DIM;
    float s = 0.f;
#pragma unroll
    for (int i = 0; i < DIM / 64; ++i) s += xv[i] * wr[lane + 64 * i];
#pragma unroll
    for (int off = 32; off; off >>= 1) s += __shfl_down(s, off);
    logit[e] = s;
  }

  if (lane == 0) {
    float m = logit[0];
#pragma unroll
    for (int e = 1; e < NEXP; ++e) m = fmaxf(m, logit[e]);
    float p[NEXP];
#pragma unroll
    for (int e = 0; e < NEXP; ++e) p[e] = expf(logit[e] - m);
    int i1 = 0;
#pragma unroll
    for (int e = 1; e < NEXP; ++e) if (p[e] > p[i1]) i1 = e;
    int i2 = (i1 == 0) ? 1 : 0;
#pragma unroll
    for (int e = 0; e < NEXP; ++e)
      if (e != i1 && p[e] > p[i2]) i2 = e;
    float denom = p[i1] + p[i2];
    float g1 = p[i1] / denom;
    float g2 = p[i2] / denom;

    int pos1 = atomicAdd(&counts[i1], 1);
    toklist[i1 * N_TOK + pos1] = n;
    tokexp[n * 2 + 0] = i1; tokpos[n * 2 + 0] = pos1; tokgate[n * 2 + 0] = g1;

    int pos2 = atomicAdd(&counts[i2], 1);
    toklist[i2 * N_TOK + pos2] = n;
    tokexp[n * 2 + 1] = i2; tokpos[n * 2 + 1] = pos2; tokgate[n * 2 + 1] = g2;
  }
}

// ---------------- bf16 MFMA GEMM tiles: 128x128x32, 256 thr, 4 waves 2x2 ----------------
#define BM 128
#define BN 128
#define BK 32

// fc1: Abuf[base+r, f] = relu(x[tok[r],:] . W1[e,f,:])^2, bf16 out
__global__ __launch_bounds__(256) void fc1_mfma(
    const float* __restrict__ x, const float* __restrict__ W1,
    const int* __restrict__ counts, const int* __restrict__ toklist,
    __hip_bfloat16* __restrict__ Abuf) {
  const int ROWB = N_TOK / BM;   // 16
  const int COLB = FDIM / BN;    // 16
  int bid = blockIdx.x;
  int e  = bid / (ROWB * COLB);
  int rb = (bid / COLB) % ROWB;
  int cb = bid % COLB;
  int ne = counts[e];
  if (rb * BM >= ne) return;
  int base = 0;
  for (int i = 0; i < e; ++i) base += counts[i];

  __shared__ ushort_t As[BM][BK];   // 8 KiB
  __shared__ ushort_t Bs[BN][BK];   // 8 KiB

  int tid = threadIdx.x;
  int srow = tid >> 1;             // 0..127 staged row
  int skc  = (tid & 1) * 16;       // k-chunk (elements)

  int grow = rb * BM + srow;
  int tok = toklist[e * N_TOK + ((grow < ne) ? grow : (ne - 1))];
  const float* arow = x + (size_t)tok * DIM + skc;
  const float* brow = W1 + ((size_t)e * FDIM + (size_t)(cb * BN + srow)) * DIM + skc;

  int lane = tid & 63;
  int wave = tid >> 6;
  int wr = (wave >> 1) * 64, wc = (wave & 1) * 64;
  int lr  = lane & 15;
  int lkb = (lane >> 4) * 8;

  f32x4 acc[4][4] = {};

  for (int k0 = 0; k0 < DIM; k0 += BK) {
    float4 a0 = *(const float4*)(arow + k0);
    float4 a1 = *(const float4*)(arow + k0 + 4);
    float4 a2 = *(const float4*)(arow + k0 + 8);
    float4 a3 = *(const float4*)(arow + k0 + 12);
    float4 b0 = *(const float4*)(brow + k0);
    float4 b1 = *(const float4*)(brow + k0 + 4);
    float4 b2 = *(const float4*)(brow + k0 + 8);
    float4 b3 = *(const float4*)(brow + k0 + 12);
    uint4 ua0 = make_uint4(cvt2(a0.x,a0.y), cvt2(a0.z,a0.w), cvt2(a1.x,a1.y), cvt2(a1.z,a1.w));
    uint4 ua1 = make_uint4(cvt2(a2.x,a2.y), cvt2(a2.z,a2.w), cvt2(a3.x,a3.y), cvt2(a3.z,a3.w));
    uint4 ub0 = make_uint4(cvt2(b0.x,b0.y), cvt2(b0.z,b0.w), cvt2(b1.x,b1.y), cvt2(b1.z,b1.w));
    uint4 ub1 = make_uint4(cvt2(b2.x,b2.y), cvt2(b2.z,b2.w), cvt2(b3.x,b3.y), cvt2(b3.z,b3.w));
    __syncthreads();
    *(uint4*)&As[srow][skc]     = ua0;
    *(uint4*)&As[srow][skc + 8] = ua1;
    *(uint4*)&Bs[srow][skc]     = ub0;
    *(uint4*)&Bs[srow][skc + 8] = ub1;
    __syncthreads();
    short8 af[4], bfr[4];
#pragma unroll
    for (int m = 0; m < 4; ++m) af[m]  = *(const short8*)&As[wr + m * 16 + lr][lkb];
#pragma unroll
    for (int n = 0; n < 4; ++n) bfr[n] = *(const short8*)&Bs[wc + n * 16 + lr][lkb];
#pragma unroll
    for (int m = 0; m < 4; ++m)
#pragma unroll
      for (int n = 0; n < 4; ++n)
        acc[m][n] = __builtin_amdgcn_mfma_f32_16x16x32_bf16(af[m], bfr[n], acc[m][n], 0, 0, 0);
  }

  int colbase = cb * BN + wc + lr;
#pragma unroll
  for (int m = 0; m < 4; ++m) {
#pragma unroll
    for (int j = 0; j < 4; ++j) {
      int r = rb * BM + wr + m * 16 + (lane >> 4) * 4 + j;
      if (r < ne) {
        __hip_bfloat16* orow = Abuf + (size_t)(base + r) * FDIM + colbase;
#pragma unroll
        for (int n = 0; n < 4; ++n) {
          float v = fmaxf(acc[m][n][j], 0.f);
          v *= v;
          orow[n * 16] = __float2bfloat16(v);
        }
      }
    }
  }
}

// fc2: Ybuf[base+r, d] = Abuf[base+r,:] . W2[e,d,:], fp32 out
__global__ __launch_bounds__(256) void fc2_mfma(
    const __hip_bfloat16* __restrict__ Abuf, const float* __restrict__ W2,
    const int* __restrict__ counts, float* __restrict__ Ybuf) {
  const int ROWB = N_TOK / BM;   // 16
  const int COLB = DIM / BN;     // 8
  int bid = blockIdx.x;
  int e  = bid / (ROWB * COLB);
  int rb = (bid / COLB) % ROWB;
  int cb = bid % COLB;
  int ne = counts[e];
  if (rb * BM >= ne) return;
  int base = 0;
  for (int i = 0; i < e; ++i) base += counts[i];

  __shared__ ushort_t As[BM][BK];
  __shared__ ushort_t Bs[BN][BK];

  int tid = threadIdx.x;
  int srow = tid >> 1;
  int skc  = (tid & 1) * 16;

  int grow = rb * BM + srow;
  int arow_idx = base + ((grow < ne) ? grow : (ne - 1));
  const ushort_t* arow = (const ushort_t*)Abuf + (size_t)arow_idx * FDIM + skc;
  const float* brow = W2 + ((size_t)e * DIM + (size_t)(cb * BN + srow)) * FDIM + skc;

  int lane = tid & 63;
  int wave = tid >> 6;
  int wr = (wave >> 1) * 64, wc = (wave & 1) * 64;
  int lr  = lane & 15;
  int lkb = (lane >> 4) * 8;

  f32x4 acc[4][4] = {};

  for (int k0 = 0; k0 < FDIM; k0 += BK) {
    uint4 ua0 = *(const uint4*)(arow + k0);      // 8 bf16
    uint4 ua1 = *(const uint4*)(arow + k0 + 8);  // 8 bf16
    float4 b0 = *(const float4*)(brow + k0);
    float4 b1 = *(const float4*)(brow + k0 + 4);
    float4 b2 = *(const float4*)(brow + k0 + 8);
    float4 b3 = *(const float4*)(brow + k0 + 12);
    uint4 ub0 = make_uint4(cvt2(b0.x,b0.y), cvt2(b0.z,b0.w), cvt2(b1.x,b1.y), cvt2(b1.z,b1.w));
    uint4 ub1 = make_uint4(cvt2(b2.x,b2.y), cvt2(b2.z,b2.w), cvt2(b3.x,b3.y), cvt2(b3.z,b3.w));
    __syncthreads();
    *(uint4*)&As[srow][skc]     = ua0;
    *(uint4*)&As[srow][skc + 8] = ua1;
    *(uint4*)&Bs[srow][skc]     = ub0;
    *(uint4*)&Bs[srow][skc + 8] = ub1;
    __syncthreads();
    short8 af[4], bfr[4];
#pragma unroll
    for (int m = 0; m < 4; ++m) af[m]  = *(const short8*)&As[wr + m * 16 + lr][lkb];
#pragma unroll
    for (int n = 0; n < 4; ++n) bfr[n] = *(const short8*)&Bs[wc + n * 16 + lr][lkb];
#pragma unroll
    for (int m = 0; m < 4; ++m)
#pragma unroll
      for (int n = 0; n < 4; ++n)
        acc[m][n] = __builtin_amdgcn_mfma_f32_16x16x32_bf16(af[m], bfr[n], acc[m][n], 0, 0, 0);
  }

  int colbase = cb * BN + wc + lr;
#pragma unroll
  for (int m = 0; m < 4; ++m) {
#pragma unroll
    for (int j = 0; j < 4; ++j) {
      int r = rb * BM + wr + m * 16 + (lane >> 4) * 4 + j;
      if (r < ne) {
        float* orow = Ybuf + (size_t)(base + r) * DIM + colbase;
#pragma unroll
        for (int n = 0; n < 4; ++n) orow[n * 16] = acc[m][n][j];
      }
    }
  }
}

// ---------------- combine: out[n] = g0*Y[row0] + g1*Y[row1] ----------------
__global__ __launch_bounds__(256) void combine_kernel(
    const float* __restrict__ Ybuf, const int* __restrict__ counts,
    const int* __restrict__ tokexp, const int* __restrict__ tokpos,
    const float* __restrict__ tokgate, float* __restrict__ out) {
  int n = blockIdx.x;
  int c4 = threadIdx.x * 4;

  int e0 = tokexp[n * 2 + 0], p0 = tokpos[n * 2 + 0];
  int e1 = tokexp[n * 2 + 1], p1 = tokpos[n * 2 + 1];
  float g0 = tokgate[n * 2 + 0], g1 = tokgate[n * 2 + 1];

  int b0 = 0, b1 = 0;
#pragma unroll
  for (int i = 0; i < NEXP; ++i) {
    int c = counts[i];
    if (i < e0) b0 += c;
    if (i < e1) b1 += c;
  }

  float4 y0 = *(const float4*)&Ybuf[(size_t)(b0 + p0) * DIM + c4];
  float4 y1 = *(const float4*)&Ybuf[(size_t)(b1 + p1) * DIM + c4];
  float4 o;
  o.x = g0 * y0.x + g1 * y1.x;
  o.y = g0 * y0.y + g1 * y1.y;
  o.z = g0 * y0.z + g1 * y1.z;
  o.w = g0 * y0.w + g1 * y1.w;
  *(float4*)&out[(size_t)n * DIM + c4] = o;
}

extern "C" void kernel_launch(void* const* d_in, const int* in_sizes, int n_in,
                              void* d_out, int out_size, void* d_ws, size_t ws_size,
                              hipStream_t stream) {
  const float* x  = (const float*)d_in[0];
  const float* Wr = (const float*)d_in[1];
  const float* W1 = (const float*)d_in[2];
  const float* W2 = (const float*)d_in[3];
  float* out = (float*)d_out;

  char* ws = (char*)d_ws;
  int*   counts  = (int*)(ws + OFF_COUNTS);
  int*   toklist = (int*)(ws + OFF_TOK);
  int*   tokexp  = (int*)(ws + OFF_TOKEXP);
  int*   tokpos  = (int*)(ws + OFF_TOKPOS);
  float* tokgate = (float*)(ws + OFF_TOKGATE);
  __hip_bfloat16* Abuf = (__hip_bfloat16*)(ws + OFF_A);
  float* Ybuf    = (float*)(ws + OFF_Y);

  (void)hipMemsetAsync(counts, 0, NEXP * sizeof(int), stream);

  router_kernel<<<N_TOK, 64, 0, stream>>>(x, Wr, counts, toklist, tokexp, tokpos, tokgate);

  fc1_mfma<<<NEXP * (N_TOK / BM) * (FDIM / BN), 256, 0, stream>>>(x, W1, counts, toklist, Abuf);

  fc2_mfma<<<NEXP * (N_TOK / BM) * (DIM / BN), 256, 0, stream>>>(Abuf, W2, counts, Ybuf);

  combine_kernel<<<N_TOK, 256, 0, stream>>>(Ybuf, counts, tokexp, tokpos, tokgate, out);
}

// Round 5
// 401.754 us; speedup vs baseline: 2.0777x; 1.0038x over previous
//
#include <hip/hip_runtime.h>
#include <hip/hip_bf16.h>
#include <cstdint>
#include <cstddef>

// B=1, T=2048, D=1024, E=8, F=2048, K=2. fp32 in/out; bf16 MFMA internally.
#define N_TOK 2048
#define DIM   1024
#define NEXP  8
#define FDIM  2048

#define BM 128
#define BN 128
#define BK 64

typedef __attribute__((ext_vector_type(8))) short short8;   // 8 x bf16
typedef __attribute__((ext_vector_type(4))) float f32x4;    // MFMA C/D
typedef unsigned short ushort_t;

// ---- workspace layout (bytes) ----
#define OFF_COUNTS  0
#define OFF_TOK     4096
#define OFF_GATE    (OFF_TOK + NEXP * N_TOK * 4)
#define OFF_A       ((size_t)1 << 20)   // Abuf bf16: 4096 x 2048 x 2 = 16 MiB
// total ~17 MiB

__device__ __forceinline__ uint32_t cvt2(float lo, float hi) {
  __hip_bfloat162 p = __float22bfloat162_rn(make_float2(lo, hi));
  uint32_t r; __builtin_memcpy(&r, &p, 4); return r;
}

// ---------------- router: 1 wave per token (fp32, exact) ----------------
__global__ __launch_bounds__(64) void router_kernel(
    const float* __restrict__ x, const float* __restrict__ Wr,
    int* __restrict__ counts, int* __restrict__ toklist,
    float* __restrict__ gatelist) {
  int n = blockIdx.x;
  int lane = threadIdx.x;
  const float* xr = x + (size_t)n * DIM;

  float xv[DIM / 64];
#pragma unroll
  for (int i = 0; i < DIM / 64; ++i) xv[i] = xr[lane + 64 * i];

  float logit[NEXP];
#pragma unroll
  for (int e = 0; e < NEXP; ++e) {
    const float* wr = Wr + (size_t)e * DIM;
    float s = 0.f;
#pragma unroll
    for (int i = 0; i < DIM / 64; ++i) s += xv[i] * wr[lane + 64 * i];
#pragma unroll
    for (int off = 32; off; off >>= 1) s += __shfl_down(s, off);
    logit[e] = s;
  }

  if (lane == 0) {
    float m = logit[0];
#pragma unroll
    for (int e = 1; e < NEXP; ++e) m = fmaxf(m, logit[e]);
    float p[NEXP];
#pragma unroll
    for (int e = 0; e < NEXP; ++e) p[e] = expf(logit[e] - m);
    int i1 = 0;
#pragma unroll
    for (int e = 1; e < NEXP; ++e) if (p[e] > p[i1]) i1 = e;
    int i2 = (i1 == 0) ? 1 : 0;
#pragma unroll
    for (int e = 0; e < NEXP; ++e)
      if (e != i1 && p[e] > p[i2]) i2 = e;
    float denom = p[i1] + p[i2];

    int pos1 = atomicAdd(&counts[i1], 1);
    toklist[i1 * N_TOK + pos1] = n;
    gatelist[i1 * N_TOK + pos1] = p[i1] / denom;

    int pos2 = atomicAdd(&counts[i2], 1);
    toklist[i2 * N_TOK + pos2] = n;
    gatelist[i2 * N_TOK + pos2] = p[i2] / denom;
  }
}

// ---------------- fc1: Abuf[base+r, f] = relu(x[tok[r],:] . W1[e,f,:])^2 ----------------
// 128x128x64 tile, dbuf LDS, XOR-swizzled, 4 waves of 64x64, reg-staged fp32->bf16.
__global__ __launch_bounds__(256, 2) void fc1_mfma(
    const float* __restrict__ x, const float* __restrict__ W1,
    const int* __restrict__ counts, const int* __restrict__ toklist,
    __hip_bfloat16* __restrict__ Abuf) {
  const int ROWB = N_TOK / BM;     // 16
  const int COLB = FDIM / BN;      // 16
  int bid = blockIdx.x;
  int e  = bid / (ROWB * COLB);
  int rb = (bid / COLB) % ROWB;
  int cb = bid % COLB;
  int ne = counts[e];
  if (rb * BM >= ne) return;
  int base = 0;
  for (int i = 0; i < e; ++i) base += counts[i];

  __shared__ ushort_t As[2][BM * BK];   // 2 x 16 KiB
  __shared__ ushort_t Bs[2][BN * BK];   // 2 x 16 KiB

  int tid = threadIdx.x;
  int srow = tid >> 1;            // 0..127
  int sc0  = (tid & 1) * 32;      // element col within BK
  int swzS = (srow & 7) << 3;     // element-unit XOR swizzle

  int tokr = rb * BM + srow;
  int tok = toklist[e * N_TOK + (tokr < ne ? tokr : ne - 1)];
  const float* aptr = x + (size_t)tok * DIM + sc0;
  const float* bptr = W1 + ((size_t)e * FDIM + cb * BN + srow) * DIM + sc0;

  int lane = tid & 63, wave = tid >> 6;
  int wr = (wave >> 1) * 64, wc = (wave & 1) * 64;
  int lr = lane & 15, lg = lane >> 4;

  float4 fA[8], fB[8];

#define LOADG(k0) do { _Pragma("unroll") for (int i = 0; i < 8; ++i) { \
    fA[i] = *(const float4*)(aptr + (k0) + i * 4); \
    fB[i] = *(const float4*)(bptr + (k0) + i * 4); } } while (0)

#define WRITEL(b) do { ushort_t* ap_ = &As[b][srow * BK]; ushort_t* bp_ = &Bs[b][srow * BK]; \
    _Pragma("unroll") for (int i = 0; i < 4; ++i) { \
      int ko_ = (sc0 + 8 * i) ^ swzS; \
      *(uint4*)&ap_[ko_] = make_uint4(cvt2(fA[2*i].x, fA[2*i].y), cvt2(fA[2*i].z, fA[2*i].w), \
                                      cvt2(fA[2*i+1].x, fA[2*i+1].y), cvt2(fA[2*i+1].z, fA[2*i+1].w)); \
      *(uint4*)&bp_[ko_] = make_uint4(cvt2(fB[2*i].x, fB[2*i].y), cvt2(fB[2*i].z, fB[2*i].w), \
                                      cvt2(fB[2*i+1].x, fB[2*i+1].y), cvt2(fB[2*i+1].z, fB[2*i+1].w)); \
    } } while (0)

  f32x4 acc[4][4] = {};

  LOADG(0);
  WRITEL(0);
  __syncthreads();

  const int NT = DIM / BK;   // 16
#pragma unroll 2
  for (int t = 0; t < NT; ++t) {
    int cur = t & 1;
    if (t + 1 < NT) LOADG((t + 1) * BK);   // in flight during MFMA below
#pragma unroll
    for (int ks = 0; ks < 2; ++ks) {
      short8 af[4], bf[4];
#pragma unroll
      for (int m = 0; m < 4; ++m) {
        int row = wr + m * 16 + lr;
        af[m] = *(const short8*)&As[cur][row * BK + ((ks * 32 + lg * 8) ^ ((row & 7) << 3))];
      }
#pragma unroll
      for (int n = 0; n < 4; ++n) {
        int row = wc + n * 16 + lr;
        bf[n] = *(const short8*)&Bs[cur][row * BK + ((ks * 32 + lg * 8) ^ ((row & 7) << 3))];
      }
#pragma unroll
      for (int m = 0; m < 4; ++m)
#pragma unroll
        for (int n = 0; n < 4; ++n)
          acc[m][n] = __builtin_amdgcn_mfma_f32_16x16x32_bf16(af[m], bf[n], acc[m][n], 0, 0, 0);
    }
    if (t + 1 < NT) {
      WRITEL(cur ^ 1);      // vmcnt waits here (loads mostly landed)
      __syncthreads();
    }
  }
#undef LOADG
#undef WRITEL

  int colbase = cb * BN + wc + lr;
#pragma unroll
  for (int m = 0; m < 4; ++m) {
#pragma unroll
    for (int j = 0; j < 4; ++j) {
      int r = rb * BM + wr + m * 16 + lg * 4 + j;
      if (r < ne) {
        __hip_bfloat16* orow = Abuf + (size_t)(base + r) * FDIM + colbase;
#pragma unroll
        for (int n = 0; n < 4; ++n) {
          float v = fmaxf(acc[m][n][j], 0.f);
          orow[n * 16] = __float2bfloat16(v * v);
        }
      }
    }
  }
}

// ---------------- fc2 (split-K x2): out[tok, d] += g * (Abuf[base+r, ks0:ks0+1024] . W2[e,d,ks0:]) ----------------
__global__ __launch_bounds__(256, 2) void fc2_mfma(
    const __hip_bfloat16* __restrict__ Abuf, const float* __restrict__ W2,
    const int* __restrict__ counts, const int* __restrict__ toklist,
    const float* __restrict__ gatelist, float* __restrict__ out) {
  const int ROWB = N_TOK / BM;     // 16
  const int COLB = DIM / BN;       // 8
  int bid = blockIdx.x;
  int e  = bid / (ROWB * COLB);
  int rb = (bid / COLB) % ROWB;
  int cb = bid % COLB;
  int ks0 = blockIdx.y * (FDIM / 2);   // 0 or 1024
  int ne = counts[e];
  if (rb * BM >= ne) return;
  int base = 0;
  for (int i = 0; i < e; ++i) base += counts[i];

  __shared__ ushort_t As[2][BM * BK];
  __shared__ ushort_t Bs[2][BN * BK];

  int tid = threadIdx.x;
  int srow = tid >> 1;
  int sc0  = (tid & 1) * 32;
  int swzS = (srow & 7) << 3;

  int tokr = rb * BM + srow;
  int arow_idx = base + (tokr < ne ? tokr : ne - 1);
  const ushort_t* aptr = (const ushort_t*)Abuf + (size_t)arow_idx * FDIM + ks0 + sc0;
  const float* bptr = W2 + ((size_t)e * DIM + cb * BN + srow) * FDIM + ks0 + sc0;

  int lane = tid & 63, wave = tid >> 6;
  int wr = (wave >> 1) * 64, wc = (wave & 1) * 64;
  int lr = lane & 15, lg = lane >> 4;

  uint4 uA[4];
  float4 fB[8];

#define LOADG(k0) do { \
    _Pragma("unroll") for (int i = 0; i < 4; ++i) uA[i] = *(const uint4*)(aptr + (k0) + 8 * i); \
    _Pragma("unroll") for (int i = 0; i < 8; ++i) fB[i] = *(const float4*)(bptr + (k0) + i * 4); \
  } while (0)

#define WRITEL(b) do { ushort_t* ap_ = &As[b][srow * BK]; ushort_t* bp_ = &Bs[b][srow * BK]; \
    _Pragma("unroll") for (int i = 0; i < 4; ++i) { \
      int ko_ = (sc0 + 8 * i) ^ swzS; \
      *(uint4*)&ap_[ko_] = uA[i]; \
      *(uint4*)&bp_[ko_] = make_uint4(cvt2(fB[2*i].x, fB[2*i].y), cvt2(fB[2*i].z, fB[2*i].w), \
                                      cvt2(fB[2*i+1].x, fB[2*i+1].y), cvt2(fB[2*i+1].z, fB[2*i+1].w)); \
    } } while (0)

  f32x4 acc[4][4] = {};

  LOADG(0);
  WRITEL(0);
  __syncthreads();

  const int NT = (FDIM / 2) / BK;   // 16
#pragma unroll 2
  for (int t = 0; t < NT; ++t) {
    int cur = t & 1;
    if (t + 1 < NT) LOADG((t + 1) * BK);
#pragma unroll
    for (int ks = 0; ks < 2; ++ks) {
      short8 af[4], bf[4];
#pragma unroll
      for (int m = 0; m < 4; ++m) {
        int row = wr + m * 16 + lr;
        af[m] = *(const short8*)&As[cur][row * BK + ((ks * 32 + lg * 8) ^ ((row & 7) << 3))];
      }
#pragma unroll
      for (int n = 0; n < 4; ++n) {
        int row = wc + n * 16 + lr;
        bf[n] = *(const short8*)&Bs[cur][row * BK + ((ks * 32 + lg * 8) ^ ((row & 7) << 3))];
      }
#pragma unroll
      for (int m = 0; m < 4; ++m)
#pragma unroll
        for (int n = 0; n < 4; ++n)
          acc[m][n] = __builtin_amdgcn_mfma_f32_16x16x32_bf16(af[m], bf[n], acc[m][n], 0, 0, 0);
    }
    if (t + 1 < NT) {
      WRITEL(cur ^ 1);
      __syncthreads();
    }
  }
#undef LOADG
#undef WRITEL

  // epilogue: gated atomic accumulate into out (out pre-zeroed)
  int colbase = cb * BN + wc + lr;
#pragma unroll
  for (int m = 0; m < 4; ++m) {
#pragma unroll
    for (int j = 0; j < 4; ++j) {
      int r = rb * BM + wr + m * 16 + lg * 4 + j;
      if (r < ne) {
        int tok = toklist[e * N_TOK + r];
        float g = gatelist[e * N_TOK + r];
        float* orow = out + (size_t)tok * DIM + colbase;
#pragma unroll
        for (int n = 0; n < 4; ++n)
          atomicAdd(&orow[n * 16], g * acc[m][n][j]);
      }
    }
  }
}

extern "C" void kernel_launch(void* const* d_in, const int* in_sizes, int n_in,
                              void* d_out, int out_size, void* d_ws, size_t ws_size,
                              hipStream_t stream) {
  const float* x  = (const float*)d_in[0];
  const float* Wr = (const float*)d_in[1];
  const float* W1 = (const float*)d_in[2];
  const float* W2 = (const float*)d_in[3];
  float* out = (float*)d_out;

  char* ws = (char*)d_ws;
  int*   counts   = (int*)(ws + OFF_COUNTS);
  int*   toklist  = (int*)(ws + OFF_TOK);
  float* gatelist = (float*)(ws + OFF_GATE);
  __hip_bfloat16* Abuf = (__hip_bfloat16*)(ws + OFF_A);

  (void)hipMemsetAsync(counts, 0, NEXP * sizeof(int), stream);
  (void)hipMemsetAsync(out, 0, (size_t)out_size * sizeof(float), stream);

  router_kernel<<<N_TOK, 64, 0, stream>>>(x, Wr, counts, toklist, gatelist);

  fc1_mfma<<<NEXP * (N_TOK / BM) * (FDIM / BN), 256, 0, stream>>>(x, W1, counts, toklist, Abuf);

  fc2_mfma<<<dim3(NEXP * (N_TOK / BM) * (DIM / BN), 2), 256, 0, stream>>>(
      Abuf, W2, counts, toklist, gatelist, out);
}

// Round 6
// 293.856 us; speedup vs baseline: 2.8406x; 1.3672x over previous
//
#include <hip/hip_runtime.h>
#include <hip/hip_bf16.h>
#include <cstdint>
#include <cstddef>

// B=1, T=2048, D=1024, E=8, F=2048, K=2. fp32 in/out; bf16 MFMA internally.
#define N_TOK 2048
#define DIM   1024
#define NEXP  8
#define FDIM  2048

#define BM 128
#define BN 128
#define BK 64

typedef __attribute__((ext_vector_type(8))) short short8;   // 8 x bf16
typedef __attribute__((ext_vector_type(4))) float f32x4;    // MFMA C/D
typedef unsigned short ushort_t;

// ---- workspace layout (bytes) ----
#define OFF_COUNTS  0
#define OFF_TOK     4096
#define OFF_GATE    (OFF_TOK + NEXP * N_TOK * 4)
#define OFF_A       ((size_t)1 << 20)                              // Abuf bf16: 4096x2048x2 = 16 MiB
#define OFF_W1B     (OFF_A  + (size_t)2 * N_TOK * FDIM * 2)        // W1 bf16: 32 MiB
#define OFF_W2B     (OFF_W1B + (size_t)NEXP * FDIM * DIM * 2)      // W2 bf16: 32 MiB
#define OFF_XB      (OFF_W2B + (size_t)NEXP * DIM * FDIM * 2)      // x bf16: 4 MiB
// total ~85.1 MiB

__device__ __forceinline__ uint32_t cvt2(float lo, float hi) {
  __hip_bfloat162 p = __float22bfloat162_rn(make_float2(lo, hi));
  uint32_t r; __builtin_memcpy(&r, &p, 4); return r;
}

// async global->LDS, 16B per lane; LDS dest is wave-uniform base + lane*16
__device__ __forceinline__ void gl16(const ushort_t* g, const ushort_t* l) {
  __builtin_amdgcn_global_load_lds(
      (const __attribute__((address_space(1))) void*)g,
      (__attribute__((address_space(3))) void*)l, 16, 0, 0);
}

// ---------------- prep: fp32 -> bf16 for W1, W2, x ----------------
#define W1_U8 ((size_t)NEXP * FDIM * DIM / 8)   // 2,097,152 units of 8 elems
#define W2_U8 W1_U8
#define X_U8  ((size_t)N_TOK * DIM / 8)         // 262,144
__global__ __launch_bounds__(256) void prep_kernel(
    const float* __restrict__ W1, const float* __restrict__ W2, const float* __restrict__ x,
    ushort_t* __restrict__ W1b, ushort_t* __restrict__ W2b, ushort_t* __restrict__ xb) {
  size_t stride = (size_t)gridDim.x * 256;
  for (size_t u = (size_t)blockIdx.x * 256 + threadIdx.x; u < W1_U8 + W2_U8 + X_U8; u += stride) {
    const float* s; ushort_t* d; size_t o;
    if (u < W1_U8)              { s = W1; d = W1b; o = u; }
    else if (u < W1_U8 + W2_U8) { s = W2; d = W2b; o = u - W1_U8; }
    else                        { s = x;  d = xb;  o = u - W1_U8 - W2_U8; }
    float4 a = *(const float4*)(s + o * 8);
    float4 b = *(const float4*)(s + o * 8 + 4);
    *(uint4*)(d + o * 8) = make_uint4(cvt2(a.x, a.y), cvt2(a.z, a.w), cvt2(b.x, b.y), cvt2(b.z, b.w));
  }
}

// ---------------- router: 1 wave per token (fp32, exact) ----------------
__global__ __launch_bounds__(64) void router_kernel(
    const float* __restrict__ x, const float* __restrict__ Wr,
    int* __restrict__ counts, int* __restrict__ toklist,
    float* __restrict__ gatelist) {
  int n = blockIdx.x;
  int lane = threadIdx.x;
  const float* xr = x + (size_t)n * DIM;

  float xv[DIM / 64];
#pragma unroll
  for (int i = 0; i < DIM / 64; ++i) xv[i] = xr[lane + 64 * i];

  float logit[NEXP];
#pragma unroll
  for (int e = 0; e < NEXP; ++e) {
    const float* wr = Wr + (size_t)e * DIM;
    float s = 0.f;
#pragma unroll
    for (int i = 0; i < DIM / 64; ++i) s += xv[i] * wr[lane + 64 * i];
#pragma unroll
    for (int off = 32; off; off >>= 1) s += __shfl_down(s, off);
    logit[e] = s;
  }

  if (lane == 0) {
    float m = logit[0];
#pragma unroll
    for (int e = 1; e < NEXP; ++e) m = fmaxf(m, logit[e]);
    float p[NEXP];
#pragma unroll
    for (int e = 0; e < NEXP; ++e) p[e] = expf(logit[e] - m);
    int i1 = 0;
#pragma unroll
    for (int e = 1; e < NEXP; ++e) if (p[e] > p[i1]) i1 = e;
    int i2 = (i1 == 0) ? 1 : 0;
#pragma unroll
    for (int e = 0; e < NEXP; ++e)
      if (e != i1 && p[e] > p[i2]) i2 = e;
    float denom = p[i1] + p[i2];

    int pos1 = atomicAdd(&counts[i1], 1);
    toklist[i1 * N_TOK + pos1] = n;
    gatelist[i1 * N_TOK + pos1] = p[i1] / denom;

    int pos2 = atomicAdd(&counts[i2], 1);
    toklist[i2 * N_TOK + pos2] = n;
    gatelist[i2 * N_TOK + pos2] = p[i2] / denom;
  }
}

// ---------------- fc1: Abuf[base+r, f] = relu(xb[tok[r],:] . W1b[e,f,:])^2 ----------------
// m97 structure: 128x128x64 tile, single 32KB LDS buffer, global_load_lds staging,
// source-side XOR swizzle (col16 ^= row&7), 4 waves 2x2, 3 blocks/CU.
__global__ __launch_bounds__(256, 3) void fc1_mfma(
    const ushort_t* __restrict__ xb, const ushort_t* __restrict__ W1b,
    const int* __restrict__ counts, const int* __restrict__ toklist,
    __hip_bfloat16* __restrict__ Abuf) {
  const int ROWB = N_TOK / BM;     // 16
  const int COLB = FDIM / BN;      // 16
  int bid = blockIdx.x;
  int e  = bid / (ROWB * COLB);
  int rb = (bid / COLB) % ROWB;
  int cb = bid % COLB;
  int ne = counts[e];
  if (rb * BM >= ne) return;
  int base = 0;
  for (int i = 0; i < e; ++i) base += counts[i];

  __shared__ ushort_t As[BM * BK];   // 16 KiB
  __shared__ ushort_t Bs[BN * BK];   // 16 KiB

  int tid = threadIdx.x, lane = tid & 63, w = tid >> 6;

  // gload addressing: LDS slot (w,i,lane) covers row = w*32+i*8+(lane>>3), col16 = lane&7.
  // Source fetches col16 ^ (row&7) so swizzled reads below see linear data.
  const ushort_t* gA[4]; const ushort_t* gB[4];
  const ushort_t* lA[4]; const ushort_t* lB[4];
#pragma unroll
  for (int i = 0; i < 4; ++i) {
    int row = w * 32 + i * 8 + (lane >> 3);
    int c16 = (lane & 7) ^ (row & 7);
    int r = rb * BM + row; if (r >= ne) r = ne - 1;
    int tok = toklist[e * N_TOK + r];
    gA[i] = xb + (size_t)tok * DIM + c16 * 8;
    gB[i] = W1b + ((size_t)e * FDIM + cb * BN + row) * DIM + c16 * 8;
    lA[i] = &As[w * 2048 + i * 512];
    lB[i] = &Bs[w * 2048 + i * 512];
  }

  int wr = (w >> 1) * 64, wc = (w & 1) * 64;
  int lr = lane & 15, lg = lane >> 4;
  f32x4 acc[4][4] = {};

  for (int t = 0; t < DIM / BK; ++t) {
    __syncthreads();   // prev tile fully consumed
#pragma unroll
    for (int i = 0; i < 4; ++i) {
      gl16(gA[i], lA[i]); gl16(gB[i], lB[i]);
      gA[i] += BK; gB[i] += BK;
    }
    __syncthreads();   // compiler drains vmcnt(0) before barrier -> tile ready
#pragma unroll
    for (int ks = 0; ks < 2; ++ks) {
      short8 af[4], bf[4];
#pragma unroll
      for (int m = 0; m < 4; ++m) {
        int row = wr + m * 16 + lr;
        af[m] = *(const short8*)&As[row * BK + (((ks * 4 + lg) ^ (row & 7)) * 8)];
      }
#pragma unroll
      for (int n = 0; n < 4; ++n) {
        int row = wc + n * 16 + lr;
        bf[n] = *(const short8*)&Bs[row * BK + (((ks * 4 + lg) ^ (row & 7)) * 8)];
      }
#pragma unroll
      for (int m = 0; m < 4; ++m)
#pragma unroll
        for (int n = 0; n < 4; ++n)
          acc[m][n] = __builtin_amdgcn_mfma_f32_16x16x32_bf16(af[m], bf[n], acc[m][n], 0, 0, 0);
    }
  }

  int colbase = cb * BN + wc + lr;
#pragma unroll
  for (int m = 0; m < 4; ++m) {
#pragma unroll
    for (int j = 0; j < 4; ++j) {
      int r = rb * BM + wr + m * 16 + lg * 4 + j;
      if (r < ne) {
        __hip_bfloat16* orow = Abuf + (size_t)(base + r) * FDIM + colbase;
#pragma unroll
        for (int n = 0; n < 4; ++n) {
          float v = fmaxf(acc[m][n][j], 0.f);
          orow[n * 16] = __float2bfloat16(v * v);
        }
      }
    }
  }
}

// ---------------- fc2 (split-K x2): out[tok,d] += g * (Abuf[base+r, ks0:+1024] . W2b[e,d,ks0:]) ----------------
__global__ __launch_bounds__(256, 3) void fc2_mfma(
    const ushort_t* __restrict__ Abuf, const ushort_t* __restrict__ W2b,
    const int* __restrict__ counts, const int* __restrict__ toklist,
    const float* __restrict__ gatelist, float* __restrict__ out) {
  const int ROWB = N_TOK / BM;     // 16
  const int COLB = DIM / BN;       // 8
  int bid = blockIdx.x;
  int e  = bid / (ROWB * COLB);
  int rb = (bid / COLB) % ROWB;
  int cb = bid % COLB;
  int ks0 = blockIdx.y * (FDIM / 2);   // 0 or 1024
  int ne = counts[e];
  if (rb * BM >= ne) return;
  int base = 0;
  for (int i = 0; i < e; ++i) base += counts[i];

  __shared__ ushort_t As[BM * BK];
  __shared__ ushort_t Bs[BN * BK];

  int tid = threadIdx.x, lane = tid & 63, w = tid >> 6;

  const ushort_t* gA[4]; const ushort_t* gB[4];
  const ushort_t* lA[4]; const ushort_t* lB[4];
#pragma unroll
  for (int i = 0; i < 4; ++i) {
    int row = w * 32 + i * 8 + (lane >> 3);
    int c16 = (lane & 7) ^ (row & 7);
    int r = rb * BM + row; if (r >= ne) r = ne - 1;
    gA[i] = Abuf + (size_t)(base + r) * FDIM + ks0 + c16 * 8;
    gB[i] = W2b + ((size_t)e * DIM + cb * BN + row) * FDIM + ks0 + c16 * 8;
    lA[i] = &As[w * 2048 + i * 512];
    lB[i] = &Bs[w * 2048 + i * 512];
  }

  int wr = (w >> 1) * 64, wc = (w & 1) * 64;
  int lr = lane & 15, lg = lane >> 4;
  f32x4 acc[4][4] = {};

  for (int t = 0; t < (FDIM / 2) / BK; ++t) {
    __syncthreads();
#pragma unroll
    for (int i = 0; i < 4; ++i) {
      gl16(gA[i], lA[i]); gl16(gB[i], lB[i]);
      gA[i] += BK; gB[i] += BK;
    }
    __syncthreads();
#pragma unroll
    for (int ks = 0; ks < 2; ++ks) {
      short8 af[4], bf[4];
#pragma unroll
      for (int m = 0; m < 4; ++m) {
        int row = wr + m * 16 + lr;
        af[m] = *(const short8*)&As[row * BK + (((ks * 4 + lg) ^ (row & 7)) * 8)];
      }
#pragma unroll
      for (int n = 0; n < 4; ++n) {
        int row = wc + n * 16 + lr;
        bf[n] = *(const short8*)&Bs[row * BK + (((ks * 4 + lg) ^ (row & 7)) * 8)];
      }
#pragma unroll
      for (int m = 0; m < 4; ++m)
#pragma unroll
        for (int n = 0; n < 4; ++n)
          acc[m][n] = __builtin_amdgcn_mfma_f32_16x16x32_bf16(af[m], bf[n], acc[m][n], 0, 0, 0);
    }
  }

  // epilogue: gated atomic accumulate into out (out pre-zeroed)
  int colbase = cb * BN + wc + lr;
#pragma unroll
  for (int m = 0; m < 4; ++m) {
#pragma unroll
    for (int j = 0; j < 4; ++j) {
      int r = rb * BM + wr + m * 16 + lg * 4 + j;
      if (r < ne) {
        int tok = toklist[e * N_TOK + r];
        float g = gatelist[e * N_TOK + r];
        float* orow = out + (size_t)tok * DIM + colbase;
#pragma unroll
        for (int n = 0; n < 4; ++n)
          atomicAdd(&orow[n * 16], g * acc[m][n][j]);
      }
    }
  }
}

extern "C" void kernel_launch(void* const* d_in, const int* in_sizes, int n_in,
                              void* d_out, int out_size, void* d_ws, size_t ws_size,
                              hipStream_t stream) {
  const float* x  = (const float*)d_in[0];
  const float* Wr = (const float*)d_in[1];
  const float* W1 = (const float*)d_in[2];
  const float* W2 = (const float*)d_in[3];
  float* out = (float*)d_out;

  char* ws = (char*)d_ws;
  int*   counts   = (int*)(ws + OFF_COUNTS);
  int*   toklist  = (int*)(ws + OFF_TOK);
  float* gatelist = (float*)(ws + OFF_GATE);
  __hip_bfloat16* Abuf = (__hip_bfloat16*)(ws + OFF_A);
  ushort_t* W1b = (ushort_t*)(ws + OFF_W1B);
  ushort_t* W2b = (ushort_t*)(ws + OFF_W2B);
  ushort_t* xb  = (ushort_t*)(ws + OFF_XB);

  (void)hipMemsetAsync(counts, 0, NEXP * sizeof(int), stream);
  (void)hipMemsetAsync(out, 0, (size_t)out_size * sizeof(float), stream);

  prep_kernel<<<4096, 256, 0, stream>>>(W1, W2, x, W1b, W2b, xb);

  router_kernel<<<N_TOK, 64, 0, stream>>>(x, Wr, counts, toklist, gatelist);

  fc1_mfma<<<NEXP * (N_TOK / BM) * (FDIM / BN), 256, 0, stream>>>(
      xb, W1b, counts, toklist, Abuf);

  fc2_mfma<<<dim3(NEXP * (N_TOK / BM) * (DIM / BN), 2), 256, 0, stream>>>(
      (const ushort_t*)Abuf, W2b, counts, toklist, gatelist, out);
}